// Round 1
// baseline (1468.532 us; speedup 1.0000x reference)
//
#include <hip/hip_runtime.h>
#include <math.h>

#define IN_DIM 256
#define OUT_D 64
#define ROUTIT 4
#define LDS_CAP 40   // staged edges per node: 4 nodes * 40 * 256B = 40KB -> 4 blocks/CU

// ---------------- h = l2norm(l2norm(leaky_relu(x @ W + b))) ----------------
__global__ __launch_bounds__(256) void gemm_norm_kernel(
    const float* __restrict__ x, const float* __restrict__ w,
    const float* __restrict__ bias, float* __restrict__ h, int n)
{
    int lane = threadIdx.x & 63;
    int wid  = threadIdx.x >> 6;
    int row  = blockIdx.x * 4 + wid;
    if (row >= n) return;
    const float* xr = x + (size_t)row * IN_DIM;
    float acc = bias[lane];
    for (int i0 = 0; i0 < IN_DIM; i0 += 64) {
        float xv = xr[i0 + lane];             // coalesced 256B, wave-shared row
        #pragma unroll
        for (int j = 0; j < 64; ++j) {
            float xb = __shfl(xv, j, 64);
            acc = fmaf(xb, w[(i0 + j) * OUT_D + lane], acc);
        }
    }
    acc = (acc > 0.0f) ? acc : 0.01f * acc;   // leaky_relu, slope 0.01
    #pragma unroll
    for (int r = 0; r < 2; ++r) {             // reference normalizes twice
        float ss = acc * acc;
        ss += __shfl_xor(ss, 1, 64);
        ss += __shfl_xor(ss, 2, 64);
        ss += __shfl_xor(ss, 4, 64);
        acc = acc / fmaxf(sqrtf(ss), 1e-12f);
    }
    h[(size_t)row * OUT_D + lane] = acc;
}

// ---------------- CSR build by target ----------------
__global__ __launch_bounds__(256) void count_kernel(
    const int* __restrict__ trg, int m, int* __restrict__ counts)
{
    int e = blockIdx.x * 256 + threadIdx.x;
    if (e < m) atomicAdd(&counts[trg[e]], 1);
}

__global__ __launch_bounds__(1024) void scan_kernel(
    const int* __restrict__ counts, int* __restrict__ row_start,
    int* __restrict__ cursor, int n)
{
    __shared__ int tmp[1024];
    __shared__ int carry_s;
    if (threadIdx.x == 0) carry_s = 0;
    __syncthreads();
    for (int base = 0; base < n; base += 1024) {
        int i = base + (int)threadIdx.x;
        int val = (i < n) ? counts[i] : 0;
        tmp[threadIdx.x] = val;
        __syncthreads();
        for (int off = 1; off < 1024; off <<= 1) {
            int t = (threadIdx.x >= (unsigned)off) ? tmp[threadIdx.x - off] : 0;
            __syncthreads();
            tmp[threadIdx.x] += t;
            __syncthreads();
        }
        int carry = carry_s;
        int exc = carry + tmp[threadIdx.x] - val;  // exclusive
        if (i < n) { row_start[i] = exc; cursor[i] = exc; }
        __syncthreads();
        if (threadIdx.x == 1023) carry_s = carry + tmp[1023];
        __syncthreads();
    }
    if (threadIdx.x == 0) row_start[n] = carry_s;
}

__global__ __launch_bounds__(256) void fill_kernel(
    const int* __restrict__ trg, const int* __restrict__ src, int m,
    int* __restrict__ cursor, int* __restrict__ edge_src)
{
    int e = blockIdx.x * 256 + threadIdx.x;
    if (e < m) {
        int pos = atomicAdd(&cursor[trg[e]], 1);
        edge_src[pos] = src[e];
    }
}

// ---------------- routing: wave per node, fully local over 4 iterations ----------------
__device__ __forceinline__ void route_body(float z, float c, float& acc)
{
    // capsule dot (8 lanes per capsule)
    float p = z * c;
    p += __shfl_xor(p, 1, 64);
    p += __shfl_xor(p, 2, 64);
    p += __shfl_xor(p, 4, 64);
    // softmax over the 8 capsules (lane-stride-8 butterfly)
    float mx = p;
    mx = fmaxf(mx, __shfl_xor(mx, 8, 64));
    mx = fmaxf(mx, __shfl_xor(mx, 16, 64));
    mx = fmaxf(mx, __shfl_xor(mx, 32, 64));
    float ex = __expf(p - mx);
    float sm = ex;
    sm += __shfl_xor(sm, 8, 64);
    sm += __shfl_xor(sm, 16, 64);
    sm += __shfl_xor(sm, 32, 64);
    acc = fmaf(ex / sm, z, acc);
}

__global__ __launch_bounds__(256) void route_kernel(
    const float* __restrict__ h, const int* __restrict__ row_start,
    const int* __restrict__ edge_src, float* __restrict__ out, int n)
{
    __shared__ float zbuf[4][LDS_CAP][OUT_D];
    int lane = threadIdx.x & 63;
    int wid  = threadIdx.x >> 6;
    int v = blockIdx.x * 4 + wid;
    if (v >= n) return;
    int beg = row_start[v];
    int deg = row_start[v + 1] - beg;
    int nl  = deg < LDS_CAP ? deg : LDS_CAP;

    // lane-parallel preload of first 64 source indices (removes scalar-load chain)
    int myidx = 0;
    if (lane < deg) myidx = edge_src[beg + lane];

    for (int e = 0; e < nl; ++e) {
        int s = __shfl(myidx, e, 64);
        zbuf[wid][e][lane] = h[(size_t)s * OUT_D + lane];   // coalesced 256B
    }

    float c = h[(size_t)v * OUT_D + lane];
    #pragma unroll
    for (int it = 0; it < ROUTIT; ++it) {
        float acc = 0.0f;
        for (int e = 0; e < nl; ++e) {
            float z = zbuf[wid][e][lane];
            route_body(z, c, acc);
        }
        for (int e = nl; e < deg; ++e) {                    // rare overflow path
            int s = edge_src[beg + e];
            float z = h[(size_t)s * OUT_D + lane];
            route_body(z, c, acc);
        }
        c += acc;
        float ss = c * c;                                    // per-capsule l2norm
        ss += __shfl_xor(ss, 1, 64);
        ss += __shfl_xor(ss, 2, 64);
        ss += __shfl_xor(ss, 4, 64);
        c = c / fmaxf(sqrtf(ss), 1e-12f);
    }
    out[(size_t)v * OUT_D + lane] = c;
}

// ---------------- launch ----------------
extern "C" void kernel_launch(void* const* d_in, const int* in_sizes, int n_in,
                              void* d_out, int out_size, void* d_ws, size_t ws_size,
                              hipStream_t stream)
{
    const float* x       = (const float*)d_in[0];
    const int*   src_trg = (const int*)d_in[1];
    const float* w       = (const float*)d_in[2];
    const float* bias    = (const float*)d_in[3];
    float*       out     = (float*)d_out;

    int n = in_sizes[0] / IN_DIM;   // 50000
    int m = in_sizes[1] / 2;        // 1638400
    const int* trg = src_trg;       // row 0 = trg
    const int* src = src_trg + m;   // row 1 = src

    char* wsb = (char*)d_ws;
    size_t off = 0;
    float* h        = (float*)(wsb + off); off += (size_t)n * OUT_D * sizeof(float);
    int*   counts   = (int*)(wsb + off);   off += (size_t)n * sizeof(int);
    int*   rowstart = (int*)(wsb + off);   off += (size_t)(n + 1) * sizeof(int);
    off = (off + 255) & ~(size_t)255;
    int*   cursor   = (int*)(wsb + off);   off += (size_t)n * sizeof(int);
    int*   edgesrc  = (int*)(wsb + off);   off += (size_t)m * sizeof(int);

    hipMemsetAsync(counts, 0, (size_t)n * sizeof(int), stream);
    gemm_norm_kernel<<<(n + 3) / 4, 256, 0, stream>>>(x, w, bias, h, n);
    count_kernel<<<(m + 255) / 256, 256, 0, stream>>>(trg, m, counts);
    scan_kernel<<<1, 1024, 0, stream>>>(counts, rowstart, cursor, n);
    fill_kernel<<<(m + 255) / 256, 256, 0, stream>>>(trg, src, m, cursor, edgesrc);
    route_kernel<<<(n + 3) / 4, 256, 0, stream>>>(h, rowstart, edgesrc, out, n);
}

// Round 2
// 690.592 us; speedup vs baseline: 2.1265x; 2.1265x over previous
//
#include <hip/hip_runtime.h>
#include <math.h>

#define IN_DIM 256
#define OUT_D 64
#define ROUTIT 4
#define RSTRIDE 68   // floats per staged edge: 64 + 4 pad -> <=2-way LDS bank aliasing
#define LDS_CAP 48   // staged edges/node (multiple of 8); deg>48 is ~0.4% of nodes

// ---- cross-lane helpers: xor1/2 via DPP quad_perm, xor8 via DPP row_ror:8 (VALU pipe),
// ---- xor4/16 via ds_swizzle, xor32 via shfl (DS pipe)
__device__ __forceinline__ float dpp_add_xor1(float x) {
    return x + __int_as_float(__builtin_amdgcn_mov_dpp(__float_as_int(x), 0xB1, 0xF, 0xF, true));
}
__device__ __forceinline__ float dpp_add_xor2(float x) {
    return x + __int_as_float(__builtin_amdgcn_mov_dpp(__float_as_int(x), 0x4E, 0xF, 0xF, true));
}
__device__ __forceinline__ float dpp_add_xor8(float x) {
    return x + __int_as_float(__builtin_amdgcn_mov_dpp(__float_as_int(x), 0x128, 0xF, 0xF, true));
}
__device__ __forceinline__ float swz_add_xor4(float x) {
    return x + __int_as_float(__builtin_amdgcn_ds_swizzle(__float_as_int(x), 0x101F));
}
__device__ __forceinline__ float swz_add_xor16(float x) {
    return x + __int_as_float(__builtin_amdgcn_ds_swizzle(__float_as_int(x), 0x401F));
}

// ---------------- h = l2norm(l2norm(leaky_relu(x @ W + b))) ----------------
// lane = row; acc[64] in VGPRs; w/bias addresses are wave-uniform -> scalar loads.
// No cross-lane ops at all.
__global__ __launch_bounds__(256) void gemm_norm_kernel(
    const float* __restrict__ x, const float* __restrict__ w,
    const float* __restrict__ bias, float* __restrict__ h, int n)
{
    int lane = threadIdx.x & 63;
    int wid  = threadIdx.x >> 6;
    int row  = (blockIdx.x * 4 + wid) * 64 + lane;
    int rc   = row < n ? row : n - 1;
    float acc[OUT_D];
    #pragma unroll
    for (int c = 0; c < OUT_D; ++c) acc[c] = bias[c];
    const float* xr = x + (size_t)rc * IN_DIM;
    for (int j0 = 0; j0 < IN_DIM; j0 += 4) {
        float4 xv = *(const float4*)(xr + j0);
        const float* wr = w + (size_t)j0 * OUT_D;
        #pragma unroll
        for (int jj = 0; jj < 4; ++jj) {
            float xs = (jj == 0) ? xv.x : (jj == 1) ? xv.y : (jj == 2) ? xv.z : xv.w;
            #pragma unroll
            for (int c = 0; c < OUT_D; ++c)
                acc[c] = fmaf(xs, wr[jj * OUT_D + c], acc[c]);
        }
    }
    if (row < n) {
        #pragma unroll
        for (int c = 0; c < OUT_D; ++c) {
            float v = acc[c];
            acc[c] = v > 0.0f ? v : 0.01f * v;     // leaky_relu
        }
        #pragma unroll
        for (int r = 0; r < 2; ++r) {              // reference normalizes twice
            #pragma unroll
            for (int kb = 0; kb < 8; ++kb) {
                float ss = 0.0f;
                #pragma unroll
                for (int d = 0; d < 8; ++d) ss = fmaf(acc[kb*8+d], acc[kb*8+d], ss);
                float inv = 1.0f / fmaxf(sqrtf(ss), 1e-12f);
                #pragma unroll
                for (int d = 0; d < 8; ++d) acc[kb*8+d] *= inv;
            }
        }
        float* hr = h + (size_t)row * OUT_D;
        #pragma unroll
        for (int c0 = 0; c0 < OUT_D; c0 += 4) {
            float4 o; o.x = acc[c0]; o.y = acc[c0+1]; o.z = acc[c0+2]; o.w = acc[c0+3];
            *(float4*)(hr + c0) = o;
        }
    }
}

// ---------------- CSR build by target ----------------
__global__ __launch_bounds__(256) void count_kernel(
    const int* __restrict__ trg, int m, int* __restrict__ counts)
{
    int e = blockIdx.x * 256 + threadIdx.x;
    if (e < m) atomicAdd(&counts[trg[e]], 1);
}

// single block, wave-scan based prefix sum (4 barriers per 1024-chunk)
__global__ __launch_bounds__(1024) void scan_kernel(
    const int* __restrict__ counts, int* __restrict__ row_start,
    int* __restrict__ cursor, int n)
{
    __shared__ int wsum[16];
    __shared__ int carry_s;
    int lane = threadIdx.x & 63;
    int wv   = threadIdx.x >> 6;
    if (threadIdx.x == 0) carry_s = 0;
    __syncthreads();
    for (int base = 0; base < n; base += 1024) {
        int i = base + (int)threadIdx.x;
        int val = (i < n) ? counts[i] : 0;
        int s = val;
        #pragma unroll
        for (int off = 1; off < 64; off <<= 1) {
            int t = __shfl_up(s, off, 64);
            if (lane >= off) s += t;
        }
        if (lane == 63) wsum[wv] = s;
        __syncthreads();
        if (wv == 0) {
            int t = (lane < 16) ? wsum[lane] : 0;
            #pragma unroll
            for (int off = 1; off < 16; off <<= 1) {
                int u = __shfl_up(t, off, 64);
                if (lane >= off) t += u;
            }
            if (lane < 16) wsum[lane] = t;
        }
        __syncthreads();
        int carry   = carry_s;
        int waveoff = (wv == 0) ? 0 : wsum[wv - 1];
        if (i < n) {
            int exc = carry + waveoff + s - val;
            row_start[i] = exc;
            cursor[i]    = exc;
        }
        __syncthreads();
        if (threadIdx.x == 0) carry_s = carry + wsum[15];
        __syncthreads();
    }
    if (threadIdx.x == 0) row_start[n] = carry_s;
}

__global__ __launch_bounds__(256) void fill_kernel(
    const int* __restrict__ trg, const int* __restrict__ src, int m,
    int* __restrict__ cursor, int* __restrict__ edge_src)
{
    int e = blockIdx.x * 256 + threadIdx.x;
    if (e < m) {
        int pos = atomicAdd(&cursor[trg[e]], 1);
        edge_src[pos] = src[e];
    }
}

// ---------------- routing ----------------
__device__ __forceinline__ void load8v(float z[8], const float* p) {
    float4 a = *(const float4*)p;
    float4 b = *(const float4*)(p + 4);
    z[0]=a.x; z[1]=a.y; z[2]=a.z; z[3]=a.w;
    z[4]=b.x; z[5]=b.y; z[6]=b.z; z[7]=b.w;
}

// lane = (eo = lane>>3 edge-in-octet, k = lane&7 capsule). 8 edges per group.
// |p| <= 1 (unit-norm 8-vectors) -> exp without max subtraction is exact-safe.
// A zero-padded edge contributes exactly 0 to acc (softmax is per-edge over k).
__device__ __forceinline__ void route_group(const float z[8], const float c[8], float acc[8]) {
    float p = z[0] * c[0];
    #pragma unroll
    for (int d = 1; d < 8; ++d) p = fmaf(z[d], c[d], p);
    float ex = __expf(p);               // TAU = 1
    float sm = dpp_add_xor1(ex);        // sum over the 8 capsules of this edge
    sm = dpp_add_xor2(sm);
    sm = swz_add_xor4(sm);
    float wgt = __fdividef(ex, sm);
    #pragma unroll
    for (int d = 0; d < 8; ++d) acc[d] = fmaf(wgt, z[d], acc[d]);
}

__global__ __launch_bounds__(256) void route_kernel(
    const float* __restrict__ h, const int* __restrict__ row_start,
    const int* __restrict__ edge_src, float* __restrict__ out, int n)
{
    __shared__ float zbuf[4][LDS_CAP * RSTRIDE];   // 52.2 KB, wave-private slices
    int lane = threadIdx.x & 63;
    int wid  = threadIdx.x >> 6;
    int v = blockIdx.x * 4 + wid;
    if (v >= n) return;                 // n % 4 == 0 -> whole blocks; no barriers used
    int beg = row_start[v];
    int deg = row_start[v + 1] - beg;
    int nl  = deg < LDS_CAP ? deg : LDS_CAP;
    int nl8 = (nl + 7) & ~7;

    float* zb = zbuf[wid];
    int myidx = (lane < nl) ? edge_src[beg + lane] : 0;
    for (int e = 0; e < nl; ++e) {
        int s = __shfl(myidx, e, 64);
        zb[e * RSTRIDE + lane] = h[(size_t)s * OUT_D + lane];   // coalesced 256B gather
    }
    for (int e = nl; e < nl8; ++e) zb[e * RSTRIDE + lane] = 0.0f;  // exact zero-padding

    int k = lane & 7, eo = lane >> 3;
    float c[8];
    load8v(c, h + (size_t)v * OUT_D + k * 8);

    const float* zlb = zb + eo * RSTRIDE + k * 8;
    int ngroups = nl8 >> 3;

    #pragma unroll
    for (int it = 0; it < ROUTIT; ++it) {
        float acc[8] = {0,0,0,0,0,0,0,0};
        int g = 0;
        for (; g + 2 <= ngroups; g += 2) {          // 2 groups in flight
            float z0[8], z1[8];
            load8v(z0, zlb + (size_t)(g    ) * 8 * RSTRIDE);
            load8v(z1, zlb + (size_t)(g + 1) * 8 * RSTRIDE);
            route_group(z0, c, acc);
            route_group(z1, c, acc);
        }
        if (g < ngroups) {
            float z0[8];
            load8v(z0, zlb + (size_t)g * 8 * RSTRIDE);
            route_group(z0, c, acc);
        }
        for (int e0 = LDS_CAP; e0 < deg; e0 += 8) { // rare overflow: z from global
            int eg = e0 + eo;
            float z0[8] = {0,0,0,0,0,0,0,0};
            if (eg < deg) {
                int s = edge_src[beg + eg];
                load8v(z0, h + (size_t)s * OUT_D + k * 8);
            }
            route_group(z0, c, acc);
        }
        // reduce acc over the 8 edge-octets (lanes differing in bits 3,4,5)
        float ss = 0.0f;
        #pragma unroll
        for (int d = 0; d < 8; ++d) {
            float a = acc[d];
            a = dpp_add_xor8(a);
            a = swz_add_xor16(a);
            a += __shfl_xor(a, 32, 64);
            float cv = c[d] + a;
            c[d] = cv;
            ss = fmaf(cv, cv, ss);                  // per-capsule norm, in-lane
        }
        float inv = 1.0f / fmaxf(sqrtf(ss), 1e-12f);
        #pragma unroll
        for (int d = 0; d < 8; ++d) c[d] *= inv;
    }
    if (eo == 0) {
        float* op = out + (size_t)v * OUT_D + k * 8;
        float4 o1, o2;
        o1.x=c[0]; o1.y=c[1]; o1.z=c[2]; o1.w=c[3];
        o2.x=c[4]; o2.y=c[5]; o2.z=c[6]; o2.w=c[7];
        *(float4*)op = o1;
        *(float4*)(op + 4) = o2;
    }
}

// ---------------- launch ----------------
extern "C" void kernel_launch(void* const* d_in, const int* in_sizes, int n_in,
                              void* d_out, int out_size, void* d_ws, size_t ws_size,
                              hipStream_t stream)
{
    const float* x       = (const float*)d_in[0];
    const int*   src_trg = (const int*)d_in[1];
    const float* w       = (const float*)d_in[2];
    const float* bias    = (const float*)d_in[3];
    float*       out     = (float*)d_out;

    int n = in_sizes[0] / IN_DIM;   // 50000
    int m = in_sizes[1] / 2;        // 1638400
    const int* trg = src_trg;       // row 0 = trg
    const int* src = src_trg + m;   // row 1 = src

    char* wsb = (char*)d_ws;
    size_t off = 0;
    float* h        = (float*)(wsb + off); off += (size_t)n * OUT_D * sizeof(float);
    int*   counts   = (int*)(wsb + off);   off += (size_t)n * sizeof(int);
    int*   rowstart = (int*)(wsb + off);   off += (size_t)(n + 1) * sizeof(int);
    off = (off + 255) & ~(size_t)255;
    int*   cursor   = (int*)(wsb + off);   off += (size_t)n * sizeof(int);
    int*   edgesrc  = (int*)(wsb + off);   off += (size_t)m * sizeof(int);

    hipMemsetAsync(counts, 0, (size_t)n * sizeof(int), stream);
    gemm_norm_kernel<<<((n + 63) / 64 + 3) / 4, 256, 0, stream>>>(x, w, bias, h, n);
    count_kernel<<<(m + 255) / 256, 256, 0, stream>>>(trg, m, counts);
    scan_kernel<<<1, 1024, 0, stream>>>(counts, rowstart, cursor, n);
    fill_kernel<<<(m + 255) / 256, 256, 0, stream>>>(trg, src, m, cursor, edgesrc);
    route_kernel<<<(n + 3) / 4, 256, 0, stream>>>(h, rowstart, edgesrc, out, n);
}

// Round 3
// 531.250 us; speedup vs baseline: 2.7643x; 1.2999x over previous
//
#include <hip/hip_runtime.h>
#include <math.h>

#define IN_DIM 256
#define OUT_D 64
#define ROUTIT 4
#define LCAP 48      // register-cached edges per node (6 groups of 8)
#define NG 6         // LCAP/8 fully-unrolled z-register groups

// ---- cross-lane helpers ----
// DPP (VALU pipe): xor1, xor2 via quad_perm; xor8 via row_ror:8 (within 16-lane row)
__device__ __forceinline__ float dpp_add_xor1(float x) {
    return x + __int_as_float(__builtin_amdgcn_mov_dpp(__float_as_int(x), 0xB1, 0xF, 0xF, true));
}
__device__ __forceinline__ float dpp_add_xor2(float x) {
    return x + __int_as_float(__builtin_amdgcn_mov_dpp(__float_as_int(x), 0x4E, 0xF, 0xF, true));
}
__device__ __forceinline__ float dpp_add_xor8(float x) {
    return x + __int_as_float(__builtin_amdgcn_mov_dpp(__float_as_int(x), 0x128, 0xF, 0xF, true));
}
// DS pipe (per-iteration only): xor4, xor16 via ds_swizzle; xor32 via shfl
__device__ __forceinline__ float swz_add_xor4(float x) {
    return x + __int_as_float(__builtin_amdgcn_ds_swizzle(__float_as_int(x), 0x101F));
}
__device__ __forceinline__ float swz_add_xor16(float x) {
    return x + __int_as_float(__builtin_amdgcn_ds_swizzle(__float_as_int(x), 0x401F));
}

__device__ __forceinline__ void load8v(float z[8], const float* p) {
    float4 a = *(const float4*)p;
    float4 b = *(const float4*)(p + 4);
    z[0]=a.x; z[1]=a.y; z[2]=a.z; z[3]=a.w;
    z[4]=b.x; z[5]=b.y; z[6]=b.z; z[7]=b.w;
}

// ---------------- h = l2norm(l2norm(leaky_relu(x @ W + b))) ----------------
// lane = row, wave = 16-col slice (capsules stay wave-local: 16 cols = 2 capsules).
// 4x the wave count of v1 (3128 waves); x rows re-read by the block's 4 waves -> L1/L2.
__global__ __launch_bounds__(256) void gemm_norm_kernel(
    const float* __restrict__ x, const float* __restrict__ w,
    const float* __restrict__ bias, float* __restrict__ h, int n)
{
    int lane = threadIdx.x & 63;
    int wv   = threadIdx.x >> 6;
    int row  = blockIdx.x * 64 + lane;
    int rc   = row < n ? row : n - 1;
    int c0   = wv * 16;
    float acc[16];
    #pragma unroll
    for (int c = 0; c < 16; ++c) acc[c] = bias[c0 + c];   // wave-uniform scalar loads
    const float* xr = x + (size_t)rc * IN_DIM;
    for (int j0 = 0; j0 < IN_DIM; j0 += 4) {
        float4 xv = *(const float4*)(xr + j0);
        const float* wr = w + (size_t)j0 * OUT_D + c0;
        #pragma unroll
        for (int jj = 0; jj < 4; ++jj) {
            float xs = (jj == 0) ? xv.x : (jj == 1) ? xv.y : (jj == 2) ? xv.z : xv.w;
            #pragma unroll
            for (int c = 0; c < 16; ++c)
                acc[c] = fmaf(xs, wr[jj * OUT_D + c], acc[c]);
        }
    }
    if (row < n) {
        #pragma unroll
        for (int c = 0; c < 16; ++c) {
            float v = acc[c];
            acc[c] = v > 0.0f ? v : 0.01f * v;            // leaky_relu
        }
        #pragma unroll
        for (int r = 0; r < 2; ++r) {                     // reference normalizes twice
            #pragma unroll
            for (int kb = 0; kb < 2; ++kb) {              // 2 capsules per wave slice
                float ss = 0.0f;
                #pragma unroll
                for (int d = 0; d < 8; ++d) ss = fmaf(acc[kb*8+d], acc[kb*8+d], ss);
                float inv = 1.0f / fmaxf(sqrtf(ss), 1e-12f);
                #pragma unroll
                for (int d = 0; d < 8; ++d) acc[kb*8+d] *= inv;
            }
        }
        float* hr = h + (size_t)row * OUT_D + c0;
        #pragma unroll
        for (int cc = 0; cc < 16; cc += 4) {
            float4 o; o.x = acc[cc]; o.y = acc[cc+1]; o.z = acc[cc+2]; o.w = acc[cc+3];
            *(float4*)(hr + cc) = o;
        }
    }
}

// ---------------- CSR build by target ----------------
__global__ __launch_bounds__(256) void count_kernel(
    const int* __restrict__ trg, int m, int* __restrict__ counts)
{
    int e = blockIdx.x * 256 + threadIdx.x;
    if (e < m) atomicAdd(&counts[trg[e]], 1);
}

// single block, int4-per-thread wave-scan prefix sum (13 chunks for n=50000)
__global__ __launch_bounds__(1024) void scan_kernel(
    const int* __restrict__ counts, int* __restrict__ row_start,
    int* __restrict__ cursor, int n)   // n % 4 == 0
{
    __shared__ int wsum[16];
    __shared__ int carry_s;
    int lane = threadIdx.x & 63;
    int wv   = threadIdx.x >> 6;
    int n4   = n >> 2;
    if (threadIdx.x == 0) carry_s = 0;
    __syncthreads();
    for (int base = 0; base < n4; base += 1024) {
        int i4 = base + (int)threadIdx.x;
        int4 v = make_int4(0,0,0,0);
        if (i4 < n4) v = ((const int4*)counts)[i4];
        int s0 = v.x, s1 = s0 + v.y, s2 = s1 + v.z, s3 = s2 + v.w;
        int s = s3;                                   // inclusive wave scan of thread sums
        #pragma unroll
        for (int off = 1; off < 64; off <<= 1) {
            int t = __shfl_up(s, off, 64);
            if (lane >= off) s += t;
        }
        if (lane == 63) wsum[wv] = s;
        __syncthreads();
        if (wv == 0) {
            int t = (lane < 16) ? wsum[lane] : 0;
            #pragma unroll
            for (int off = 1; off < 16; off <<= 1) {
                int u = __shfl_up(t, off, 64);
                if (lane >= off) t += u;
            }
            if (lane < 16) wsum[lane] = t;
        }
        __syncthreads();
        int carry = carry_s;
        if (i4 < n4) {
            int b = carry + ((wv == 0) ? 0 : wsum[wv - 1]) + (s - s3);  // exclusive base
            int4 rs; rs.x = b; rs.y = b + s0; rs.z = b + s1; rs.w = b + s2;
            ((int4*)row_start)[i4] = rs;
            ((int4*)cursor)[i4]    = rs;
        }
        __syncthreads();
        if (threadIdx.x == 0) carry_s = carry + wsum[15];
        __syncthreads();
    }
    if (threadIdx.x == 0) row_start[n] = carry_s;
}

__global__ __launch_bounds__(256) void fill_kernel(
    const int* __restrict__ trg, const int* __restrict__ src, int m,
    int* __restrict__ cursor, int* __restrict__ edge_src)
{
    int e = blockIdx.x * 256 + threadIdx.x;
    if (e < m) {
        int pos = atomicAdd(&cursor[trg[e]], 1);
        edge_src[pos] = src[e];
    }
}

// ---------------- routing: wave per node, z in registers, LDS-free ----------------
// lane mapping: capsule k = lane bits {0,1,3}; edge-in-octet eo = lane bits {2,4,5}.
// Per-edge softmax reduction (over k) = xor1/xor2/xor8 -> all DPP, zero DS ops.
// |p| <= 1 (unit-norm capsules, Cauchy-Schwarz) -> exp without max-subtract is safe.
// Zero-padded edge: p=0, wgt=1/8, contributes wgt*0 = 0 -> mathematically exact.
__device__ __forceinline__ void route_group(const float z[8], const float c[8], float acc[8]) {
    float p = z[0] * c[0];
    #pragma unroll
    for (int d = 1; d < 8; ++d) p = fmaf(z[d], c[d], p);
    float ex = __expf(p);               // TAU = 1
    float sm = dpp_add_xor1(ex);
    sm = dpp_add_xor2(sm);
    sm = dpp_add_xor8(sm);
    float wgt = __fdividef(ex, sm);
    #pragma unroll
    for (int d = 0; d < 8; ++d) acc[d] = fmaf(wgt, z[d], acc[d]);
}

__global__ __launch_bounds__(256, 4) void route_kernel(
    const float* __restrict__ h, const int* __restrict__ row_start,
    const int* __restrict__ edge_src, float* __restrict__ out, int n)
{
    int lane = threadIdx.x & 63;
    int wid  = threadIdx.x >> 6;
    int v = blockIdx.x * 4 + wid;
    if (v >= n) return;
    int beg = row_start[v];
    int deg = row_start[v + 1] - beg;
    int nl  = deg < LCAP ? deg : LCAP;
    int ngroups = (nl + 7) >> 3;

    int k  = (lane & 3) | ((lane >> 1) & 4);         // capsule: lane bits 0,1,3
    int eo = ((lane >> 2) & 1) | ((lane >> 3) & 6);  // edge-octet: lane bits 2,4,5

    float c[8];
    load8v(c, h + (size_t)v * OUT_D + k * 8);

    // z fragments: loaded once from global in compute layout, live in 48 VGPRs.
    // 4-lane clusters (same eo, k pair-block) read 128B contiguous -> coalesced.
    float z[NG][8];
    #pragma unroll
    for (int g = 0; g < NG; ++g) {
        int e = g * 8 + eo;
        if (e < nl) {
            int s = edge_src[beg + e];               // 8-lane broadcast load
            load8v(z[g], h + (size_t)s * OUT_D + k * 8);
        } else {
            #pragma unroll
            for (int d = 0; d < 8; ++d) z[g][d] = 0.0f;
        }
    }

    #pragma unroll
    for (int it = 0; it < ROUTIT; ++it) {
        float acc[8] = {0,0,0,0,0,0,0,0};
        #pragma unroll
        for (int g = 0; g < NG; ++g)
            if (g < ngroups) route_group(z[g], c, acc);   // wave-uniform guard
        if (deg > LCAP) {                                 // rare overflow (~0.4% nodes)
            for (int e0 = LCAP; e0 < deg; e0 += 8) {
                int e = e0 + eo;
                float zt[8] = {0,0,0,0,0,0,0,0};
                if (e < deg) {
                    int s = edge_src[beg + e];
                    load8v(zt, h + (size_t)s * OUT_D + k * 8);
                }
                route_group(zt, c, acc);
            }
        }
        // reduce acc over the 8 edge-octets (lane bits 2,4,5); norm is in-lane
        float ss = 0.0f;
        #pragma unroll
        for (int d = 0; d < 8; ++d) {
            float a = acc[d];
            a = swz_add_xor4(a);
            a = swz_add_xor16(a);
            a += __shfl_xor(a, 32, 64);
            float cv = c[d] + a;
            c[d] = cv;
            ss = fmaf(cv, cv, ss);
        }
        float inv = 1.0f / fmaxf(sqrtf(ss), 1e-12f);
        #pragma unroll
        for (int d = 0; d < 8; ++d) c[d] *= inv;
    }
    if (eo == 0) {                                   // lanes {0-3, 8-11} hold k=0..7
        float* op = out + (size_t)v * OUT_D + k * 8;
        float4 o1, o2;
        o1.x=c[0]; o1.y=c[1]; o1.z=c[2]; o1.w=c[3];
        o2.x=c[4]; o2.y=c[5]; o2.z=c[6]; o2.w=c[7];
        *(float4*)op = o1;
        *(float4*)(op + 4) = o2;
    }
}

// ---------------- launch ----------------
extern "C" void kernel_launch(void* const* d_in, const int* in_sizes, int n_in,
                              void* d_out, int out_size, void* d_ws, size_t ws_size,
                              hipStream_t stream)
{
    const float* x       = (const float*)d_in[0];
    const int*   src_trg = (const int*)d_in[1];
    const float* w       = (const float*)d_in[2];
    const float* bias    = (const float*)d_in[3];
    float*       out     = (float*)d_out;

    int n = in_sizes[0] / IN_DIM;   // 50000
    int m = in_sizes[1] / 2;        // 1638400
    const int* trg = src_trg;       // row 0 = trg
    const int* src = src_trg + m;   // row 1 = src

    char* wsb = (char*)d_ws;
    size_t off = 0;
    float* h        = (float*)(wsb + off); off += (size_t)n * OUT_D * sizeof(float);
    int*   counts   = (int*)(wsb + off);   off += (size_t)n * sizeof(int);
    int*   rowstart = (int*)(wsb + off);   off += (size_t)(n + 1) * sizeof(int);
    off = (off + 255) & ~(size_t)255;
    int*   cursor   = (int*)(wsb + off);   off += (size_t)n * sizeof(int);
    int*   edgesrc  = (int*)(wsb + off);   off += (size_t)m * sizeof(int);

    hipMemsetAsync(counts, 0, (size_t)n * sizeof(int), stream);
    gemm_norm_kernel<<<(n + 63) / 64, 256, 0, stream>>>(x, w, bias, h, n);
    count_kernel<<<(m + 255) / 256, 256, 0, stream>>>(trg, m, counts);
    scan_kernel<<<1, 1024, 0, stream>>>(counts, rowstart, cursor, n);
    fill_kernel<<<(m + 255) / 256, 256, 0, stream>>>(trg, src, m, cursor, edgesrc);
    route_kernel<<<(n + 3) / 4, 256, 0, stream>>>(h, rowstart, edgesrc, out, n);
}

// Round 4
// 444.227 us; speedup vs baseline: 3.3058x; 1.1959x over previous
//
#include <hip/hip_runtime.h>
#include <math.h>

#define IN_DIM 256
#define OUT_D 64
#define ROUTIT 4
#define LCAP 48      // register-cached edges per node (6 groups of 8)
#define NG 6         // LCAP/8 fully-unrolled z-register groups
#define GBLK 512     // gemm block: 8 waves x 8-col slices (one capsule per wave)

// ---- cross-lane helpers ----
__device__ __forceinline__ float dpp_add_xor1(float x) {
    return x + __int_as_float(__builtin_amdgcn_mov_dpp(__float_as_int(x), 0xB1, 0xF, 0xF, true));
}
__device__ __forceinline__ float dpp_add_xor2(float x) {
    return x + __int_as_float(__builtin_amdgcn_mov_dpp(__float_as_int(x), 0x4E, 0xF, 0xF, true));
}
__device__ __forceinline__ float dpp_add_xor8(float x) {
    return x + __int_as_float(__builtin_amdgcn_mov_dpp(__float_as_int(x), 0x128, 0xF, 0xF, true));
}
__device__ __forceinline__ float swz_add_xor4(float x) {
    return x + __int_as_float(__builtin_amdgcn_ds_swizzle(__float_as_int(x), 0x101F));
}
__device__ __forceinline__ float swz_add_xor16(float x) {
    return x + __int_as_float(__builtin_amdgcn_ds_swizzle(__float_as_int(x), 0x401F));
}

__device__ __forceinline__ void load8v(float z[8], const float* p) {
    float4 a = *(const float4*)p;
    float4 b = *(const float4*)(p + 4);
    z[0]=a.x; z[1]=a.y; z[2]=a.z; z[3]=a.w;
    z[4]=b.x; z[5]=b.y; z[6]=b.z; z[7]=b.w;
}

// ---------------- h = l2norm(l2norm(leaky_relu(x @ W + b))) ----------------
// w staged in LDS (64 KB); per-k w reads are wave-uniform ds_read_b128 broadcasts
// (~3 cyc, conflict-free) instead of 200-cyc global loads -> kills the latency chain
// that held v3 at 7.9% VALUBusy. lane = row; wave = 8-col slice = one capsule,
// so leaky+double-norm epilogue is fully lane-local.
__global__ __launch_bounds__(GBLK) void gemm_norm_kernel(
    const float* __restrict__ x, const float* __restrict__ w,
    const float* __restrict__ bias, float* __restrict__ h, int n)
{
    __shared__ float wlds[IN_DIM * OUT_D];   // 64 KB -> 2 blocks/CU (16 waves)
    {
        const float4* wsrc = (const float4*)w;
        float4* wdst = (float4*)wlds;
        #pragma unroll
        for (int i = 0; i < (IN_DIM * OUT_D / 4); i += GBLK)
            wdst[i + threadIdx.x] = wsrc[i + threadIdx.x];   // 8 coalesced iters
    }
    __syncthreads();

    int lane = threadIdx.x & 63;
    int wv   = threadIdx.x >> 6;          // 0..7
    int c0   = wv * 8;                    // this wave's capsule
    int row  = blockIdx.x * 64 + lane;
    int rc   = row < n ? row : n - 1;
    const float* xr = x + (size_t)rc * IN_DIM;

    float acc[8];
    #pragma unroll
    for (int c = 0; c < 8; ++c) acc[c] = bias[c0 + c];   // wave-uniform

    float4 xa = *(const float4*)(xr);
    float4 xb = *(const float4*)(xr + 4);
    #pragma unroll 2
    for (int k0 = 0; k0 < IN_DIM; k0 += 8) {
        int kn = (k0 + 8 < IN_DIM) ? k0 + 8 : 0;          // wrap: harmless re-read
        float4 na = *(const float4*)(xr + kn);            // prefetch next 8 k
        float4 nb = *(const float4*)(xr + kn + 4);
        float xs[8] = {xa.x, xa.y, xa.z, xa.w, xb.x, xb.y, xb.z, xb.w};
        const float* wk = wlds + k0 * OUT_D + c0;
        #pragma unroll
        for (int kk = 0; kk < 8; ++kk) {
            float4 w0 = *(const float4*)(wk + kk * OUT_D);      // ds_read_b128 bcast
            float4 w1 = *(const float4*)(wk + kk * OUT_D + 4);
            acc[0] = fmaf(xs[kk], w0.x, acc[0]);
            acc[1] = fmaf(xs[kk], w0.y, acc[1]);
            acc[2] = fmaf(xs[kk], w0.z, acc[2]);
            acc[3] = fmaf(xs[kk], w0.w, acc[3]);
            acc[4] = fmaf(xs[kk], w1.x, acc[4]);
            acc[5] = fmaf(xs[kk], w1.y, acc[5]);
            acc[6] = fmaf(xs[kk], w1.z, acc[6]);
            acc[7] = fmaf(xs[kk], w1.w, acc[7]);
        }
        xa = na; xb = nb;
    }

    if (row < n) {
        #pragma unroll
        for (int c = 0; c < 8; ++c) {
            float v = acc[c];
            acc[c] = v > 0.0f ? v : 0.01f * v;            // leaky_relu
        }
        #pragma unroll
        for (int r = 0; r < 2; ++r) {                     // reference normalizes twice
            float ss = 0.0f;
            #pragma unroll
            for (int d = 0; d < 8; ++d) ss = fmaf(acc[d], acc[d], ss);
            float inv = 1.0f / fmaxf(sqrtf(ss), 1e-12f);
            #pragma unroll
            for (int d = 0; d < 8; ++d) acc[d] *= inv;
        }
        float* hr = h + (size_t)row * OUT_D + c0;
        float4 o1, o2;
        o1.x=acc[0]; o1.y=acc[1]; o1.z=acc[2]; o1.w=acc[3];
        o2.x=acc[4]; o2.y=acc[5]; o2.z=acc[6]; o2.w=acc[7];
        *(float4*)hr = o1;
        *(float4*)(hr + 4) = o2;
    }
}

// ---------------- CSR build by target (int4: 4 edges/thread) ----------------
__global__ __launch_bounds__(256) void count_kernel(
    const int* __restrict__ trg, int m4, int* __restrict__ counts)
{
    int i = blockIdx.x * 256 + threadIdx.x;
    if (i < m4) {
        int4 t = ((const int4*)trg)[i];
        atomicAdd(&counts[t.x], 1);
        atomicAdd(&counts[t.y], 1);
        atomicAdd(&counts[t.z], 1);
        atomicAdd(&counts[t.w], 1);
    }
}

// single block, int4-per-thread wave-scan prefix sum
__global__ __launch_bounds__(1024) void scan_kernel(
    const int* __restrict__ counts, int* __restrict__ row_start,
    int* __restrict__ cursor, int n)   // n % 4 == 0
{
    __shared__ int wsum[16];
    __shared__ int carry_s;
    int lane = threadIdx.x & 63;
    int wv   = threadIdx.x >> 6;
    int n4   = n >> 2;
    if (threadIdx.x == 0) carry_s = 0;
    __syncthreads();
    for (int base = 0; base < n4; base += 1024) {
        int i4 = base + (int)threadIdx.x;
        int4 v = make_int4(0,0,0,0);
        if (i4 < n4) v = ((const int4*)counts)[i4];
        int s0 = v.x, s1 = s0 + v.y, s2 = s1 + v.z, s3 = s2 + v.w;
        int s = s3;
        #pragma unroll
        for (int off = 1; off < 64; off <<= 1) {
            int t = __shfl_up(s, off, 64);
            if (lane >= off) s += t;
        }
        if (lane == 63) wsum[wv] = s;
        __syncthreads();
        if (wv == 0) {
            int t = (lane < 16) ? wsum[lane] : 0;
            #pragma unroll
            for (int off = 1; off < 16; off <<= 1) {
                int u = __shfl_up(t, off, 64);
                if (lane >= off) t += u;
            }
            if (lane < 16) wsum[lane] = t;
        }
        __syncthreads();
        int carry = carry_s;
        if (i4 < n4) {
            int b = carry + ((wv == 0) ? 0 : wsum[wv - 1]) + (s - s3);
            int4 rs; rs.x = b; rs.y = b + s0; rs.z = b + s1; rs.w = b + s2;
            ((int4*)row_start)[i4] = rs;
            ((int4*)cursor)[i4]    = rs;
        }
        __syncthreads();
        if (threadIdx.x == 0) carry_s = carry + wsum[15];
        __syncthreads();
    }
    if (threadIdx.x == 0) row_start[n] = carry_s;
}

__global__ __launch_bounds__(256) void fill_kernel(
    const int* __restrict__ trg, const int* __restrict__ src, int m4,
    int* __restrict__ cursor, int* __restrict__ edge_src)
{
    int i = blockIdx.x * 256 + threadIdx.x;
    if (i < m4) {
        int4 t = ((const int4*)trg)[i];
        int4 s = ((const int4*)src)[i];
        edge_src[atomicAdd(&cursor[t.x], 1)] = s.x;
        edge_src[atomicAdd(&cursor[t.y], 1)] = s.y;
        edge_src[atomicAdd(&cursor[t.z], 1)] = s.z;
        edge_src[atomicAdd(&cursor[t.w], 1)] = s.w;
    }
}

// ---------------- routing: wave per node, z in registers, LDS-free ----------------
// lane mapping: capsule k = lane bits {0,1,3}; edge-in-octet eo = lane bits {2,4,5}.
// Per-edge softmax reduction (over k) = xor1/xor2/xor8 -> all DPP, zero DS ops.
// |p| <= 1 (unit-norm capsules) -> exp without max-subtract is safe.
// Zero-padded edge contributes exactly 0 to acc.
__device__ __forceinline__ void route_group(const float z[8], const float c[8], float acc[8]) {
    float p = z[0] * c[0];
    #pragma unroll
    for (int d = 1; d < 8; ++d) p = fmaf(z[d], c[d], p);
    float ex = __expf(p);               // TAU = 1
    float sm = dpp_add_xor1(ex);
    sm = dpp_add_xor2(sm);
    sm = dpp_add_xor8(sm);
    float wgt = __fdividef(ex, sm);
    #pragma unroll
    for (int d = 0; d < 8; ++d) acc[d] = fmaf(wgt, z[d], acc[d]);
}

__global__ __launch_bounds__(256, 4) void route_kernel(
    const float* __restrict__ h, const int* __restrict__ row_start,
    const int* __restrict__ edge_src, float* __restrict__ out, int n)
{
    int lane = threadIdx.x & 63;
    int wid  = threadIdx.x >> 6;
    int v = blockIdx.x * 4 + wid;
    if (v >= n) return;
    int beg = row_start[v];
    int deg = row_start[v + 1] - beg;
    int nl  = deg < LCAP ? deg : LCAP;
    int ngroups = (nl + 7) >> 3;

    int k  = (lane & 3) | ((lane >> 1) & 4);         // capsule: lane bits 0,1,3
    int eo = ((lane >> 2) & 1) | ((lane >> 3) & 6);  // edge-octet: lane bits 2,4,5

    float c[8];
    load8v(c, h + (size_t)v * OUT_D + k * 8);

    float z[NG][8];
    #pragma unroll
    for (int g = 0; g < NG; ++g) {
        int e = g * 8 + eo;
        if (e < nl) {
            int s = edge_src[beg + e];
            load8v(z[g], h + (size_t)s * OUT_D + k * 8);
        } else {
            #pragma unroll
            for (int d = 0; d < 8; ++d) z[g][d] = 0.0f;
        }
    }

    #pragma unroll
    for (int it = 0; it < ROUTIT; ++it) {
        float acc[8] = {0,0,0,0,0,0,0,0};
        #pragma unroll
        for (int g = 0; g < NG; ++g)
            if (g < ngroups) route_group(z[g], c, acc);
        if (deg > LCAP) {
            for (int e0 = LCAP; e0 < deg; e0 += 8) {
                int e = e0 + eo;
                float zt[8] = {0,0,0,0,0,0,0,0};
                if (e < deg) {
                    int s = edge_src[beg + e];
                    load8v(zt, h + (size_t)s * OUT_D + k * 8);
                }
                route_group(zt, c, acc);
            }
        }
        float ss = 0.0f;
        #pragma unroll
        for (int d = 0; d < 8; ++d) {
            float a = acc[d];
            a = swz_add_xor4(a);
            a = swz_add_xor16(a);
            a += __shfl_xor(a, 32, 64);
            float cv = c[d] + a;
            c[d] = cv;
            ss = fmaf(cv, cv, ss);
        }
        float inv = 1.0f / fmaxf(sqrtf(ss), 1e-12f);
        #pragma unroll
        for (int d = 0; d < 8; ++d) c[d] *= inv;
    }
    if (eo == 0) {
        float* op = out + (size_t)v * OUT_D + k * 8;
        float4 o1, o2;
        o1.x=c[0]; o1.y=c[1]; o1.z=c[2]; o1.w=c[3];
        o2.x=c[4]; o2.y=c[5]; o2.z=c[6]; o2.w=c[7];
        *(float4*)op = o1;
        *(float4*)(op + 4) = o2;
    }
}

// ---------------- launch ----------------
extern "C" void kernel_launch(void* const* d_in, const int* in_sizes, int n_in,
                              void* d_out, int out_size, void* d_ws, size_t ws_size,
                              hipStream_t stream)
{
    const float* x       = (const float*)d_in[0];
    const int*   src_trg = (const int*)d_in[1];
    const float* w       = (const float*)d_in[2];
    const float* bias    = (const float*)d_in[3];
    float*       out     = (float*)d_out;

    int n = in_sizes[0] / IN_DIM;   // 50000
    int m = in_sizes[1] / 2;        // 1638400 (divisible by 4)
    int m4 = m >> 2;
    const int* trg = src_trg;       // row 0 = trg
    const int* src = src_trg + m;   // row 1 = src

    char* wsb = (char*)d_ws;
    size_t off = 0;
    float* h        = (float*)(wsb + off); off += (size_t)n * OUT_D * sizeof(float);
    int*   counts   = (int*)(wsb + off);   off += (size_t)n * sizeof(int);
    int*   rowstart = (int*)(wsb + off);   off += (size_t)(n + 1) * sizeof(int);
    off = (off + 255) & ~(size_t)255;
    int*   cursor   = (int*)(wsb + off);   off += (size_t)n * sizeof(int);
    int*   edgesrc  = (int*)(wsb + off);   off += (size_t)m * sizeof(int);

    hipMemsetAsync(counts, 0, (size_t)n * sizeof(int), stream);
    gemm_norm_kernel<<<(n + 63) / 64, GBLK, 0, stream>>>(x, w, bias, h, n);
    count_kernel<<<(m4 + 255) / 256, 256, 0, stream>>>(trg, m4, counts);
    scan_kernel<<<1, 1024, 0, stream>>>(counts, rowstart, cursor, n);
    fill_kernel<<<(m4 + 255) / 256, 256, 0, stream>>>(trg, src, m4, cursor, edgesrc);
    route_kernel<<<(n + 3) / 4, 256, 0, stream>>>(h, rowstart, edgesrc, out, n);
}

// Round 5
// 301.262 us; speedup vs baseline: 4.8746x; 1.4746x over previous
//
#include <hip/hip_runtime.h>
#include <math.h>

#define IN_DIM 256
#define OUT_D 64
#define ROUTIT 4
#define LCAP 48      // register-cached edges per node (6 groups of 8)
#define NG 6         // LCAP/8 fully-unrolled z-register groups
#define GBLK 512     // gemm block: 8 waves x 8-col slices (one capsule per wave)
#define BSH 7        // bucket shift: 128 nodes per bucket
#define NBMAX 512    // supports n up to 65536

// ---- cross-lane helpers ----
__device__ __forceinline__ float dpp_add_xor1(float x) {
    return x + __int_as_float(__builtin_amdgcn_mov_dpp(__float_as_int(x), 0xB1, 0xF, 0xF, true));
}
__device__ __forceinline__ float dpp_add_xor2(float x) {
    return x + __int_as_float(__builtin_amdgcn_mov_dpp(__float_as_int(x), 0x4E, 0xF, 0xF, true));
}
__device__ __forceinline__ float dpp_add_xor8(float x) {
    return x + __int_as_float(__builtin_amdgcn_mov_dpp(__float_as_int(x), 0x128, 0xF, 0xF, true));
}
__device__ __forceinline__ float swz_add_xor4(float x) {
    return x + __int_as_float(__builtin_amdgcn_ds_swizzle(__float_as_int(x), 0x101F));
}
__device__ __forceinline__ float swz_add_xor16(float x) {
    return x + __int_as_float(__builtin_amdgcn_ds_swizzle(__float_as_int(x), 0x401F));
}

__device__ __forceinline__ void load8v(float z[8], const float* p) {
    float4 a = *(const float4*)p;
    float4 b = *(const float4*)(p + 4);
    z[0]=a.x; z[1]=a.y; z[2]=a.z; z[3]=a.w;
    z[4]=b.x; z[5]=b.y; z[6]=b.z; z[7]=b.w;
}

// ---------------- h = l2norm(l2norm(leaky_relu(x @ W + b))) ----------------
__global__ __launch_bounds__(GBLK) void gemm_norm_kernel(
    const float* __restrict__ x, const float* __restrict__ w,
    const float* __restrict__ bias, float* __restrict__ h, int n)
{
    __shared__ float wlds[IN_DIM * OUT_D];   // 64 KB
    {
        const float4* wsrc = (const float4*)w;
        float4* wdst = (float4*)wlds;
        #pragma unroll
        for (int i = 0; i < (IN_DIM * OUT_D / 4); i += GBLK)
            wdst[i + threadIdx.x] = wsrc[i + threadIdx.x];
    }
    __syncthreads();

    int lane = threadIdx.x & 63;
    int wv   = threadIdx.x >> 6;          // 0..7
    int c0   = wv * 8;                    // this wave's capsule
    int row  = blockIdx.x * 64 + lane;
    int rc   = row < n ? row : n - 1;
    const float* xr = x + (size_t)rc * IN_DIM;

    float acc[8];
    #pragma unroll
    for (int c = 0; c < 8; ++c) acc[c] = bias[c0 + c];

    float4 xa = *(const float4*)(xr);
    float4 xb = *(const float4*)(xr + 4);
    #pragma unroll 2
    for (int k0 = 0; k0 < IN_DIM; k0 += 8) {
        int kn = (k0 + 8 < IN_DIM) ? k0 + 8 : 0;
        float4 na = *(const float4*)(xr + kn);
        float4 nb = *(const float4*)(xr + kn + 4);
        float xs[8] = {xa.x, xa.y, xa.z, xa.w, xb.x, xb.y, xb.z, xb.w};
        const float* wk = wlds + k0 * OUT_D + c0;
        #pragma unroll
        for (int kk = 0; kk < 8; ++kk) {
            float4 w0 = *(const float4*)(wk + kk * OUT_D);
            float4 w1 = *(const float4*)(wk + kk * OUT_D + 4);
            acc[0] = fmaf(xs[kk], w0.x, acc[0]);
            acc[1] = fmaf(xs[kk], w0.y, acc[1]);
            acc[2] = fmaf(xs[kk], w0.z, acc[2]);
            acc[3] = fmaf(xs[kk], w0.w, acc[3]);
            acc[4] = fmaf(xs[kk], w1.x, acc[4]);
            acc[5] = fmaf(xs[kk], w1.y, acc[5]);
            acc[6] = fmaf(xs[kk], w1.z, acc[6]);
            acc[7] = fmaf(xs[kk], w1.w, acc[7]);
        }
        xa = na; xb = nb;
    }

    if (row < n) {
        #pragma unroll
        for (int c = 0; c < 8; ++c) {
            float v = acc[c];
            acc[c] = v > 0.0f ? v : 0.01f * v;            // leaky_relu
        }
        #pragma unroll
        for (int r = 0; r < 2; ++r) {
            float ss = 0.0f;
            #pragma unroll
            for (int d = 0; d < 8; ++d) ss = fmaf(acc[d], acc[d], ss);
            float inv = 1.0f / fmaxf(sqrtf(ss), 1e-12f);
            #pragma unroll
            for (int d = 0; d < 8; ++d) acc[d] *= inv;
        }
        float* hr = h + (size_t)row * OUT_D + c0;
        float4 o1, o2;
        o1.x=acc[0]; o1.y=acc[1]; o1.z=acc[2]; o1.w=acc[3];
        o2.x=acc[4]; o2.y=acc[5]; o2.z=acc[6]; o2.w=acc[7];
        *(float4*)hr = o1;
        *(float4*)(hr + 4) = o2;
    }
}

// ---------------- CSR build: two-level counting sort ----------------
// L1: 391 buckets of 128 nodes. Per-block LDS hist -> few global atomics,
// run-claimed contiguous pair writes (dense-ish lines). L2: block per bucket,
// LDS hist over 128 nodes gives rowstart for free; scatter stays in a 16KB
// L2-local region (dense lines). Kills fill_kernel's 106MB 64B-granule scatter.

__global__ __launch_bounds__(256) void bucket_hist_kernel(
    const int* __restrict__ trg, int m4, int* __restrict__ bucket_counts, int nb)
{
    __shared__ int hist[NBMAX];
    for (int i = threadIdx.x; i < nb; i += 256) hist[i] = 0;
    __syncthreads();
    int i = blockIdx.x * 256 + threadIdx.x;
    if (i < m4) {
        int4 t = ((const int4*)trg)[i];
        atomicAdd(&hist[t.x >> BSH], 1);
        atomicAdd(&hist[t.y >> BSH], 1);
        atomicAdd(&hist[t.z >> BSH], 1);
        atomicAdd(&hist[t.w >> BSH], 1);
    }
    __syncthreads();
    for (int i2 = threadIdx.x; i2 < nb; i2 += 256) {
        int c = hist[i2];
        if (c) atomicAdd(&bucket_counts[i2], c);
    }
}

__global__ __launch_bounds__(64) void bucket_scan_kernel(
    const int* __restrict__ bucket_counts, int* __restrict__ bucket_base,
    int* __restrict__ bucket_cursor, int nb, int n, int m, int* __restrict__ row_start)
{
    int lane = threadIdx.x;
    int carry = 0;
    for (int base = 0; base <= nb; base += 64) {
        int i = base + lane;
        int v = (i < nb) ? bucket_counts[i] : 0;
        int s = v;
        #pragma unroll
        for (int off = 1; off < 64; off <<= 1) {
            int t = __shfl_up(s, off, 64);
            if (lane >= off) s += t;
        }
        if (i <= nb) {
            int exc = carry + s - v;
            bucket_base[i]   = exc;
            bucket_cursor[i] = exc;
        }
        carry += __shfl(s, 63, 64);
    }
    if (lane == 0) row_start[n] = m;
}

// 4096 edges/block: LDS hist -> claim runs (1 atomic per block-bucket) -> write pairs
__global__ __launch_bounds__(256) void partition_kernel(
    const int* __restrict__ trg, const int* __restrict__ src, int m4,
    int2* __restrict__ epairs, int* __restrict__ bucket_cursor, int nb)
{
    __shared__ int hist[NBMAX];
    __shared__ int runbase[NBMAX];
    for (int i = threadIdx.x; i < nb; i += 256) hist[i] = 0;
    __syncthreads();

    int4 tv[4], sv[4];
    int base4 = blockIdx.x * 1024;
    #pragma unroll
    for (int k = 0; k < 4; ++k) {
        int i4 = base4 + k * 256 + threadIdx.x;
        if (i4 < m4) {
            tv[k] = ((const int4*)trg)[i4];
            sv[k] = ((const int4*)src)[i4];
            atomicAdd(&hist[tv[k].x >> BSH], 1);
            atomicAdd(&hist[tv[k].y >> BSH], 1);
            atomicAdd(&hist[tv[k].z >> BSH], 1);
            atomicAdd(&hist[tv[k].w >> BSH], 1);
        } else {
            tv[k] = make_int4(-1,-1,-1,-1);
            sv[k] = make_int4(0,0,0,0);
        }
    }
    __syncthreads();
    for (int i = threadIdx.x; i < nb; i += 256) {
        int c = hist[i];
        runbase[i] = c ? atomicAdd(&bucket_cursor[i], c) : 0;
    }
    __syncthreads();
    for (int i = threadIdx.x; i < nb; i += 256) hist[i] = 0;   // reuse as local cursor
    __syncthreads();
    #pragma unroll
    for (int k = 0; k < 4; ++k) {
        int tt[4] = {tv[k].x, tv[k].y, tv[k].z, tv[k].w};
        int ss[4] = {sv[k].x, sv[k].y, sv[k].z, sv[k].w};
        #pragma unroll
        for (int j = 0; j < 4; ++j) {
            int t = tt[j];
            if (t >= 0) {
                int b = t >> BSH;
                int r = atomicAdd(&hist[b], 1);
                epairs[runbase[b] + r] = make_int2(ss[j], t);
            }
        }
    }
}

// block per bucket: hist over 128 nodes -> rowstart + dense local scatter
__global__ __launch_bounds__(256) void local_csr_kernel(
    const int2* __restrict__ epairs, const int* __restrict__ bucket_base,
    int* __restrict__ row_start, int* __restrict__ edge_src, int n)
{
    __shared__ int hist[128];
    __shared__ int excl[129];
    __shared__ int cursor[128];
    int b = blockIdx.x;
    int ebeg = bucket_base[b], eend = bucket_base[b + 1];
    int node0 = b << BSH;
    if (threadIdx.x < 128) hist[threadIdx.x] = 0;
    __syncthreads();
    for (int e = ebeg + (int)threadIdx.x; e < eend; e += 256) {
        int2 p = epairs[e];
        atomicAdd(&hist[p.y - node0], 1);
    }
    __syncthreads();
    if (threadIdx.x < 64) {                       // wave 0: scan 128 counters
        int lane = threadIdx.x;
        int carry = 0;
        #pragma unroll
        for (int c = 0; c < 2; ++c) {
            int i = c * 64 + lane;
            int v = hist[i];
            int s = v;
            #pragma unroll
            for (int off = 1; off < 64; off <<= 1) {
                int t = __shfl_up(s, off, 64);
                if (lane >= off) s += t;
            }
            excl[i] = carry + s - v;
            carry += __shfl(s, 63, 64);
        }
        if (lane == 0) excl[128] = carry;
    }
    __syncthreads();
    int nh = n - node0; if (nh > 128) nh = 128;   // nodes in this bucket
    for (int i = threadIdx.x; i <= nh; i += 256)
        row_start[node0 + i] = ebeg + excl[i];
    if (threadIdx.x < 128) cursor[threadIdx.x] = excl[threadIdx.x];
    __syncthreads();
    for (int e = ebeg + (int)threadIdx.x; e < eend; e += 256) {
        int2 p = epairs[e];
        int r = atomicAdd(&cursor[p.y - node0], 1);
        edge_src[ebeg + r] = p.x;                 // dense 16KB L2-local region
    }
}

// ---------------- routing: wave per node, z in registers, LDS-free ----------------
__device__ __forceinline__ void route_group(const float z[8], const float c[8], float acc[8]) {
    float p = z[0] * c[0];
    #pragma unroll
    for (int d = 1; d < 8; ++d) p = fmaf(z[d], c[d], p);
    float ex = __expf(p);               // TAU = 1; |p|<=1 so no max-subtract needed
    float sm = dpp_add_xor1(ex);
    sm = dpp_add_xor2(sm);
    sm = dpp_add_xor8(sm);
    float wgt = __fdividef(ex, sm);
    #pragma unroll
    for (int d = 0; d < 8; ++d) acc[d] = fmaf(wgt, z[d], acc[d]);
}

__global__ __launch_bounds__(256, 4) void route_kernel(
    const float* __restrict__ h, const int* __restrict__ row_start,
    const int* __restrict__ edge_src, float* __restrict__ out, int n)
{
    int lane = threadIdx.x & 63;
    int wid  = threadIdx.x >> 6;
    int v = blockIdx.x * 4 + wid;
    if (v >= n) return;
    int beg = row_start[v];
    int deg = row_start[v + 1] - beg;
    int nl  = deg < LCAP ? deg : LCAP;
    int ngroups = (nl + 7) >> 3;

    int k  = (lane & 3) | ((lane >> 1) & 4);         // capsule: lane bits 0,1,3
    int eo = ((lane >> 2) & 1) | ((lane >> 3) & 6);  // edge-octet: lane bits 2,4,5

    float c[8];
    load8v(c, h + (size_t)v * OUT_D + k * 8);

    float z[NG][8];
    #pragma unroll
    for (int g = 0; g < NG; ++g) {
        int e = g * 8 + eo;
        if (e < nl) {
            int s = edge_src[beg + e];
            load8v(z[g], h + (size_t)s * OUT_D + k * 8);
        } else {
            #pragma unroll
            for (int d = 0; d < 8; ++d) z[g][d] = 0.0f;
        }
    }

    #pragma unroll
    for (int it = 0; it < ROUTIT; ++it) {
        float acc[8] = {0,0,0,0,0,0,0,0};
        #pragma unroll
        for (int g = 0; g < NG; ++g)
            if (g < ngroups) route_group(z[g], c, acc);
        if (deg > LCAP) {
            for (int e0 = LCAP; e0 < deg; e0 += 8) {
                int e = e0 + eo;
                float zt[8] = {0,0,0,0,0,0,0,0};
                if (e < deg) {
                    int s = edge_src[beg + e];
                    load8v(zt, h + (size_t)s * OUT_D + k * 8);
                }
                route_group(zt, c, acc);
            }
        }
        float ss = 0.0f;
        #pragma unroll
        for (int d = 0; d < 8; ++d) {
            float a = acc[d];
            a = swz_add_xor4(a);
            a = swz_add_xor16(a);
            a += __shfl_xor(a, 32, 64);
            float cv = c[d] + a;
            c[d] = cv;
            ss = fmaf(cv, cv, ss);
        }
        float inv = 1.0f / fmaxf(sqrtf(ss), 1e-12f);
        #pragma unroll
        for (int d = 0; d < 8; ++d) c[d] *= inv;
    }
    if (eo == 0) {
        float* op = out + (size_t)v * OUT_D + k * 8;
        float4 o1, o2;
        o1.x=c[0]; o1.y=c[1]; o1.z=c[2]; o1.w=c[3];
        o2.x=c[4]; o2.y=c[5]; o2.z=c[6]; o2.w=c[7];
        *(float4*)op = o1;
        *(float4*)(op + 4) = o2;
    }
}

// ---------------- launch ----------------
extern "C" void kernel_launch(void* const* d_in, const int* in_sizes, int n_in,
                              void* d_out, int out_size, void* d_ws, size_t ws_size,
                              hipStream_t stream)
{
    const float* x       = (const float*)d_in[0];
    const int*   src_trg = (const int*)d_in[1];
    const float* w       = (const float*)d_in[2];
    const float* bias    = (const float*)d_in[3];
    float*       out     = (float*)d_out;

    int n = in_sizes[0] / IN_DIM;   // 50000
    int m = in_sizes[1] / 2;        // 1638400
    int m4 = m >> 2;
    int nb = (n + 127) >> BSH;      // 391 buckets
    const int* trg = src_trg;       // row 0 = trg
    const int* src = src_trg + m;   // row 1 = src

    char* wsb = (char*)d_ws;
    size_t off = 0;
    float* h        = (float*)(wsb + off); off += (size_t)n * OUT_D * sizeof(float);
    int*   rowstart = (int*)(wsb + off);   off += (size_t)(n + 1) * sizeof(int);
    off = (off + 255) & ~(size_t)255;
    int*   edgesrc  = (int*)(wsb + off);   off += (size_t)m * sizeof(int);
    off = (off + 255) & ~(size_t)255;
    int2*  epairs   = (int2*)(wsb + off);  off += (size_t)m * sizeof(int2);
    int*   bcounts  = (int*)(wsb + off);   off += (size_t)(nb + 1) * sizeof(int);
    int*   bbase    = (int*)(wsb + off);   off += (size_t)(nb + 1) * sizeof(int);
    int*   bcursor  = (int*)(wsb + off);   off += (size_t)(nb + 1) * sizeof(int);

    hipMemsetAsync(bcounts, 0, (size_t)(nb + 1) * sizeof(int), stream);
    gemm_norm_kernel<<<(n + 63) / 64, GBLK, 0, stream>>>(x, w, bias, h, n);
    bucket_hist_kernel<<<(m4 + 255) / 256, 256, 0, stream>>>(trg, m4, bcounts, nb);
    bucket_scan_kernel<<<1, 64, 0, stream>>>(bcounts, bbase, bcursor, nb, n, m, rowstart);
    partition_kernel<<<(m4 + 1023) / 1024, 256, 0, stream>>>(trg, src, m4, epairs, bcursor, nb);
    local_csr_kernel<<<nb, 256, 0, stream>>>(epairs, bbase, rowstart, edgesrc, n);
    route_kernel<<<(n + 3) / 4, 256, 0, stream>>>(h, rowstart, edgesrc, out, n);
}